// Round 1
// 316.133 us; speedup vs baseline: 1.0214x; 1.0214x over previous
//
#include <hip/hip_runtime.h>
#include <cmath>

// LogEig -> MaxPool2d(4,2) -> ExpEig, fused, one 32x32 SPD matrix per 64-thread block.
// R3: kernel is latency-stall bound (VALUBusy 60%, LDS pipe ~55%, occupancy 31%,
// neither pipe saturated). Block = 1 wave => DS ops are program-ordered, so each
// matmul result can overwrite one of its own source buffers after the reads.
// Re-choreographed the chain onto TWO 4KB buffers (was three):
//   A=T; T2=A*A->B; T3=B*A->A; M1(regs)->B; M2=B*A->B; M3=B*A->A; rowmax->B; exp in A
// LDS 12KB -> 8KB => 20 blocks/CU (was 13), __launch_bounds__(64,5).
// Numerics untouched (absmax is at the edge): deg-9 Chebyshev log via PS (4 mm32),
// separable maxpool, deg-8 PS exp + scaling&squaring.

#define CENTER 4.5f
#define INVH   0.2857142857142857f

struct LogCoeffs { float b[16]; };  // power-basis coeffs in t=(x-4.5)/3.5, deg 9

// acc += P*Q, 32x32, P symmetric (read P[j][4rq..] == P-rows by symmetry).
__device__ __forceinline__ void mm32(const float* __restrict__ P,
                                     const float* __restrict__ Q,
                                     float a[4][4], int rq, int cq) {
#pragma unroll 8
  for (int j = 0; j < 32; ++j) {
    const float4 pv = *(const float4*)(P + j*32 + 4*rq);
    const float4 qv = *(const float4*)(Q + j*32 + 4*cq);
    const float pr[4] = {pv.x, pv.y, pv.z, pv.w};
    const float qr[4] = {qv.x, qv.y, qv.z, qv.w};
#pragma unroll
    for (int i = 0; i < 4; ++i)
#pragma unroll
      for (int e = 0; e < 4; ++e)
        a[i][e] = fmaf(pr[i], qr[e], a[i][e]);
  }
}

__device__ __forceinline__ void st32(float* __restrict__ D, const float a[4][4],
                                     int rq, int cq) {
#pragma unroll
  for (int i = 0; i < 4; ++i)
    *(float4*)(D + (4*rq + i)*32 + 4*cq) = make_float4(a[i][0], a[i][1], a[i][2], a[i][3]);
}

// a = k0*I + k1*Tt + k2*T2t  (this thread's 4x4 tile; diag iff rq==cq)
__device__ __forceinline__ void initc(float a[4][4], float k0, float k1, float k2,
                                      const float Tt[4][4], const float T2t[4][4],
                                      bool diag) {
#pragma unroll
  for (int i = 0; i < 4; ++i)
#pragma unroll
    for (int e = 0; e < 4; ++e) {
      float v = fmaf(k2, T2t[i][e], k1 * Tt[i][e]);
      if (diag && i == e) v += k0;
      a[i][e] = v;
    }
}

// a[0..3] += P[r][*] dot Q[*][4c..4c+3], 16x16 stride-16, direct row reads (no symmetry needed)
__device__ __forceinline__ void mm16(const float* __restrict__ P,
                                     const float* __restrict__ Q,
                                     float a[4], int r, int c) {
  float pr[16];
#pragma unroll
  for (int k = 0; k < 4; ++k) {
    float4 v = *(const float4*)(P + r*16 + 4*k);
    pr[4*k] = v.x; pr[4*k+1] = v.y; pr[4*k+2] = v.z; pr[4*k+3] = v.w;
  }
#pragma unroll
  for (int j = 0; j < 16; ++j) {
    float4 qv = *(const float4*)(Q + j*16 + 4*c);
    a[0] = fmaf(pr[j], qv.x, a[0]);
    a[1] = fmaf(pr[j], qv.y, a[1]);
    a[2] = fmaf(pr[j], qv.z, a[2]);
    a[3] = fmaf(pr[j], qv.w, a[3]);
  }
}

__global__ __launch_bounds__(64, 5)
void logeig_pool_expeig(const float* __restrict__ x, float* __restrict__ out,
                        LogCoeffs lc) {
  __shared__ __align__(16) float S[2048];         // 8 KB -> 20 blocks/CU
  float* A  = S;                                  // T -> T3 -> logX -> exp buffers
  float* Bv = S + 1024;                           // T2 -> M1 -> M2 -> rowmax RM[32][16]

  const int m = blockIdx.x;
  const int t = threadIdx.x;
  const int rq = t >> 3, cq = t & 7;
  const float* xg = x + (size_t)m * 1024;

  // ---- load + map to T = (X - 4.5 I)/3.5 ----
#pragma unroll
  for (int i = 0; i < 4; ++i) {
    int fi = (i*64 + t) * 4;
    float4 v = *(const float4*)(xg + fi);
    int row = fi >> 5, cb = fi & 31, dpos = row - cb;
    float* vp = (float*)&v;
#pragma unroll
    for (int e = 0; e < 4; ++e) {
      float val = vp[e];
      if (e == dpos) val -= CENTER;
      vp[e] = val * INVH;
    }
    *(float4*)(A + fi) = v;
  }
  __syncthreads();

  // own T tile -> regs
  float Tt[4][4];
#pragma unroll
  for (int i = 0; i < 4; ++i) {
    float4 v = *(const float4*)(A + (4*rq + i)*32 + 4*cq);
    Tt[i][0] = v.x; Tt[i][1] = v.y; Tt[i][2] = v.z; Tt[i][3] = v.w;
  }

  float acc[4][4];
  const bool dg = (rq == cq);

  // T2 = T*T -> Bv
#pragma unroll
  for (int i = 0; i < 4; ++i)
#pragma unroll
    for (int e = 0; e < 4; ++e) acc[i][e] = 0.0f;
  mm32(A, A, acc, rq, cq);
  float T2t[4][4];
#pragma unroll
  for (int i = 0; i < 4; ++i)
#pragma unroll
    for (int e = 0; e < 4; ++e) T2t[i][e] = acc[i][e];
  st32(Bv, acc, rq, cq);
  __syncthreads();

  // T3 = T2*T -> overwrite A (T dead in LDS; Tt/T2t live in regs; single-wave
  // block => the store cannot pass the reads in the DS pipe)
#pragma unroll
  for (int i = 0; i < 4; ++i)
#pragma unroll
    for (int e = 0; e < 4; ++e) acc[i][e] = 0.0f;
  mm32(Bv, A, acc, rq, cq);
  st32(A, acc, rq, cq);
  __syncthreads();

  // M1 = b9*T3 + b8*T2 + b7*T + b6*I  (T3 tile is in acc; all reg-resident)
  // -> overwrite Bv (T2 dead in LDS)
  {
    float m1[4][4];
    initc(m1, lc.b[6], lc.b[7], lc.b[8], Tt, T2t, dg);
#pragma unroll
    for (int i = 0; i < 4; ++i)
#pragma unroll
      for (int e = 0; e < 4; ++e) m1[i][e] = fmaf(lc.b[9], acc[i][e], m1[i][e]);
    st32(Bv, m1, rq, cq);
  }
  __syncthreads();

  // M2 = M1*T3 + (b3 I + b4 T + b5 T2) -> overwrite Bv (M1 dead after reads)
  initc(acc, lc.b[3], lc.b[4], lc.b[5], Tt, T2t, dg);
  mm32(Bv, A, acc, rq, cq);
  st32(Bv, acc, rq, cq);
  __syncthreads();

  // M3 = M2*T3 + (b0 I + b1 T + b2 T2) = log(X) -> overwrite A (T3 dead after reads)
  initc(acc, lc.b[0], lc.b[1], lc.b[2], Tt, T2t, dg);
  mm32(Bv, A, acc, rq, cq);
  st32(A, acc, rq, cq);
  __syncthreads();

  // ---- separable MaxPool 4x4 stride 2: rowmax4 then colmax4 ----
  // rowmax RM[32][16] -> Bv (M2 dead)
  {
    const int half = t >> 5, l = t & 31;
    const float* rp = A + l*32 + 16*half;
    float4 w0 = *(const float4*)(rp + 0);
    float4 w1 = *(const float4*)(rp + 4);
    float4 w2 = *(const float4*)(rp + 8);
    float4 w3 = *(const float4*)(rp + 12);
    float2 e2 = *(const float2*)(A + l*32 + 16);  // cols 16,17 (used by half 0 only)
    float v[16] = {w0.x,w0.y,w0.z,w0.w, w1.x,w1.y,w1.z,w1.w,
                   w2.x,w2.y,w2.z,w2.w, w3.x,w3.y,w3.z,w3.w};
    float rm[8];
#pragma unroll
    for (int j = 0; j < 7; ++j)
      rm[j] = fmaxf(fmaxf(v[2*j], v[2*j+1]), fmaxf(v[2*j+2], v[2*j+3]));
    rm[7] = (half == 0) ? fmaxf(fmaxf(v[14], v[15]), fmaxf(e2.x, e2.y)) : 0.0f;
    *(float4*)(Bv + l*16 + 8*half + 0) = make_float4(rm[0], rm[1], rm[2], rm[3]);
    *(float4*)(Bv + l*16 + 8*half + 4) = make_float4(rm[4], rm[5], rm[6], rm[7]);
  }
  __syncthreads();

  // stage 2: P16[i][j] = max over 4 rows of RM; tile stays in regs (mm16 mapping r=t>>2,c=t&3)
  const int r16 = t >> 2, c16 = t & 3;
  float p16[4];
  if (r16 < 15) {
    float4 m0 = *(const float4*)(Bv + (2*r16 + 0)*16 + 4*c16);
    float4 m1 = *(const float4*)(Bv + (2*r16 + 1)*16 + 4*c16);
    float4 m2 = *(const float4*)(Bv + (2*r16 + 2)*16 + 4*c16);
    float4 m3 = *(const float4*)(Bv + (2*r16 + 3)*16 + 4*c16);
    p16[0] = fmaxf(fmaxf(m0.x, m1.x), fmaxf(m2.x, m3.x));
    p16[1] = fmaxf(fmaxf(m0.y, m1.y), fmaxf(m2.y, m3.y));
    p16[2] = fmaxf(fmaxf(m0.z, m1.z), fmaxf(m2.z, m3.z));
    p16[3] = fmaxf(fmaxf(m0.w, m1.w), fmaxf(m2.w, m3.w));
    if (c16 == 3) p16[3] = 0.0f;                 // col-15 pad
  } else {
    p16[0] = p16[1] = p16[2] = p16[3] = 0.0f;    // row-15 pad
  }

  // ---- inf-norm via shuffles -> scaling ----
  float s = fabsf(p16[0]) + fabsf(p16[1]) + fabsf(p16[2]) + fabsf(p16[3]);
  s += __shfl_xor(s, 1);
  s += __shfl_xor(s, 2);                          // row sums
  s = fmaxf(s, __shfl_xor(s, 4));
  s = fmaxf(s, __shfl_xor(s, 8));
  s = fmaxf(s, __shfl_xor(s, 16));
  s = fmaxf(s, __shfl_xor(s, 32));                // global max
  int e2i; (void)frexpf(s, &e2i);
  const int sc = e2i > 0 ? e2i : 0;               // theta in [0.5,1)
  const float scale = ldexpf(1.0f, -sc);

  // exp buffers in A (logX dead after pooling stage 1):
  // Te@0, T2e@256, T3e@512, M@768 (16x16 each, stride 16)
  float* Te  = A;
  float* T2e = A + 256;
  float* T3e = A + 512;
  float* Me  = A + 768;

  float Tet[4] = {p16[0]*scale, p16[1]*scale, p16[2]*scale, p16[3]*scale};
  *(float4*)(Te + r16*16 + 4*c16) = make_float4(Tet[0], Tet[1], Tet[2], Tet[3]);
  __syncthreads();

  // exp deg-8 PS: grouped as (C2*Q3 + C1)*Q3 + C0
  const float C0_ = 1.0f, C1_ = 1.0f, C2_ = 0.5f;
  const float C3_ = 1.6666667e-1f, C4_ = 4.1666668e-2f, C5_ = 8.3333338e-3f;
  const float C6_ = 1.3888889e-3f, C7_ = 1.9841270e-4f, C8_ = 2.4801588e-5f;

  float a4[4];
  // T2e = Te*Te
  a4[0] = a4[1] = a4[2] = a4[3] = 0.0f;
  mm16(Te, Te, a4, r16, c16);
  float T2et[4] = {a4[0], a4[1], a4[2], a4[3]};
  *(float4*)(T2e + r16*16 + 4*c16) = make_float4(a4[0], a4[1], a4[2], a4[3]);
  __syncthreads();
  // T3e = T2e*Te
  a4[0] = a4[1] = a4[2] = a4[3] = 0.0f;
  mm16(T2e, Te, a4, r16, c16);
  *(float4*)(T3e + r16*16 + 4*c16) = make_float4(a4[0], a4[1], a4[2], a4[3]);
  __syncthreads();
  // M = c6 I + c7 Te + c8 T2e (tiles in regs)
#pragma unroll
  for (int e = 0; e < 4; ++e) {
    float v = fmaf(C8_, T2et[e], C7_ * Tet[e]);
    if (4*c16 + e == r16) v += C6_;
    a4[e] = v;
  }
  *(float4*)(Me + r16*16 + 4*c16) = make_float4(a4[0], a4[1], a4[2], a4[3]);
  __syncthreads();
  // R = M*T3e + (c3 I + c4 Te + c5 T2e) -> T2e slot
#pragma unroll
  for (int e = 0; e < 4; ++e) {
    float v = fmaf(C5_, T2et[e], C4_ * Tet[e]);
    if (4*c16 + e == r16) v += C3_;
    a4[e] = v;
  }
  mm16(Me, T3e, a4, r16, c16);
  *(float4*)(T2e + r16*16 + 4*c16) = make_float4(a4[0], a4[1], a4[2], a4[3]);
  __syncthreads();
  // F = R*T3e + (c0 I + c1 Te + c2 T2e) -> Te slot
#pragma unroll
  for (int e = 0; e < 4; ++e) {
    float v = fmaf(C2_, T2et[e], C1_ * Tet[e]);
    if (4*c16 + e == r16) v += C0_;
    a4[e] = v;
  }
  mm16(T2e, T3e, a4, r16, c16);
  *(float4*)(Te + r16*16 + 4*c16) = make_float4(a4[0], a4[1], a4[2], a4[3]);
  __syncthreads();

  // squarings: ping-pong A+0 <-> A+512
  int cur = 0, oth = 512;
  for (int it = 0; it < sc; ++it) {
    a4[0] = a4[1] = a4[2] = a4[3] = 0.0f;
    mm16(A + cur, A + cur, a4, r16, c16);
    *(float4*)(A + oth + r16*16 + 4*c16) = make_float4(a4[0], a4[1], a4[2], a4[3]);
    __syncthreads();
    int tmp = cur; cur = oth; oth = tmp;
  }

  // ---- write 15x15 ----
  const float* cu = A + cur;
  float* og = out + (size_t)m * 225;
#pragma unroll
  for (int w2 = 0; w2 < 4; ++w2) {
    int q = t + 64*w2;
    if (q < 225) {
      int i = q / 15, j = q % 15;
      og[q] = cu[i*16 + j];
    }
  }
}

extern "C" void kernel_launch(void* const* d_in, const int* in_sizes, int n_in,
                              void* d_out, int out_size, void* d_ws, size_t ws_size,
                              hipStream_t stream) {
  (void)n_in; (void)d_ws; (void)ws_size; (void)out_size;
  const float* x = (const float*)d_in[0];
  float* out = (float*)d_out;
  const int nmat = in_sizes[0] >> 10;

  // deg-9 Chebyshev coeffs of log on [1,8] -> power basis (host, fp64)
  LogCoeffs lc;
  {
    const double lo = 1.0, hi = 8.0;
    const double c = 0.5*(lo + hi), h = 0.5*(hi - lo), w = h / c;
    const double z = (std::sqrt(1.0 - w*w) - 1.0) / w;
    const int DEG = 9;
    double a[16] = {0};
    a[0] = std::log(c) - std::log(1.0 + z*z);
    double zk = 1.0;
    for (int k = 1; k <= DEG; ++k) { zk *= z; a[k] = -2.0 * zk / k; }
    double b[16], Tp[16], Tc[16], Tn[16];
    for (int j = 0; j < 16; ++j) { b[j] = 0; Tp[j] = 0; Tc[j] = 0; }
    Tp[0] = 1.0; Tc[1] = 1.0;
    b[0] += a[0] * Tp[0];
    for (int j = 0; j < 16; ++j) b[j] += a[1] * Tc[j];
    for (int k = 2; k <= DEG; ++k) {
      for (int j = 0; j < 16; ++j) {
        double v = -Tp[j];
        if (j > 0) v += 2.0 * Tc[j-1];
        Tn[j] = v;
      }
      for (int j = 0; j < 16; ++j) b[j] += a[k] * Tn[j];
      for (int j = 0; j < 16; ++j) { Tp[j] = Tc[j]; Tc[j] = Tn[j]; }
    }
    for (int j = 0; j < 16; ++j) lc.b[j] = (float)b[j];
  }

  logeig_pool_expeig<<<dim3(nmat), dim3(64), 0, stream>>>(x, out, lc);
}